// Round 7
// baseline (5736.823 us; speedup 1.0000x reference)
//
#include <hip/hip_runtime.h>
#include <hip/hip_bf16.h>

// Problem constants
#define Bn 256
#define Tn 336
#define KE 16

typedef __attribute__((ext_vector_type(8))) __bf16 bf16x8;
typedef __attribute__((ext_vector_type(4))) float f32x4;
typedef unsigned long long u64t;
typedef unsigned int u32t;

#define MFMA(a, b, c) __builtin_amdgcn_mfma_f32_16x16x32_bf16((a), (b), (c), 0, 0, 0)

#define PAR_X 65536   // u32 elems per x' parity buffer (8g*32r*256c)
#define PAR_H 131072  // u32 elems per h parity buffer (8g*32r*512u)

// ---------------- pack kernels (once per launch) ----------------

__global__ void pack_wh(const float* __restrict__ Wh, __bf16* __restrict__ hi,
                        __bf16* __restrict__ lo) {
    int i = blockIdx.x * 256 + threadIdx.x;  // 512*256
    int k = i >> 8, n = i & 255;
    float v = Wh[i];
    __bf16 h = (__bf16)v;
    hi[n * 512 + k] = h;
    lo[n * 512 + k] = (__bf16)(v - (float)h);
}

__global__ void pack_wx(const float* __restrict__ Wx, __bf16* __restrict__ out) {
    int i = blockIdx.x * 256 + threadIdx.x;  // 256*32
    int n = i >> 5, k = i & 31;
    out[i] = (__bf16)((k < 17) ? Wx[k * 256 + n] : 0.f);
}

__global__ void pack_split(const float* __restrict__ in, __bf16* __restrict__ hi,
                           __bf16* __restrict__ lo, int n) {
    int i = blockIdx.x * 256 + threadIdx.x;
    if (i >= n) return;
    float v = in[i];
    __bf16 h = (__bf16)v;
    hi[i] = h;
    lo[i] = (__bf16)(v - (float)h);
}

__global__ void pack_xin(const float* __restrict__ xl, const float* __restrict__ xe,
                         __bf16* __restrict__ out) {
    int i = blockIdx.x * 256 + threadIdx.x;  // 336*256*32
    int k = i & 31, b = (i >> 5) & 255, t = i >> 13;
    float v = 0.f;
    if (k == 0) v = xl[b * Tn + t];
    else if (k < 17) v = xe[(b * Tn + t) * KE + (k - 1)];
    out[i] = (__bf16)v;
}

// ---------------- tagged MALL dataflow helpers (relaxed agent = sc1) -------

__device__ __forceinline__ u64t ald(const u64t* p) {
    return __hip_atomic_load(p, __ATOMIC_RELAXED, __HIP_MEMORY_SCOPE_AGENT);
}
__device__ __forceinline__ void ast32(u32t* p, u32t v) {
    __hip_atomic_store(p, v, __ATOMIC_RELAXED, __HIP_MEMORY_SCOPE_AGENT);
}
__device__ __forceinline__ u32t tagval(u32t tag, float f) {
    union { __bf16 b; unsigned short u; } c; c.b = (__bf16)f;
    return (tag << 16) | (u32t)c.u;
}

// poll 8 tagged u32 (one 32B chunk) until all tags==want, unpack bf16 -> LDS
__device__ __forceinline__ void poll_chunk(const u32t* src, u32t want, void* dst) {
    const u64t* p = (const u64t*)src;
    const u64t w2 = ((u64t)want << 16) | ((u64t)want << 48);
    const u64t m = 0xffff0000ffff0000ull;
    u64t a0, a1, a2, a3;
    for (;;) {
        a0 = ald(p); a1 = ald(p + 1); a2 = ald(p + 2); a3 = ald(p + 3);
        if (((a0 & m) == w2) & ((a1 & m) == w2) &
            ((a2 & m) == w2) & ((a3 & m) == w2)) break;
        __builtin_amdgcn_s_sleep(1);
    }
    union { unsigned short us[8]; bf16x8 v; } r;
    r.us[0] = (unsigned short)a0; r.us[1] = (unsigned short)(a0 >> 32);
    r.us[2] = (unsigned short)a1; r.us[3] = (unsigned short)(a1 >> 32);
    r.us[4] = (unsigned short)a2; r.us[5] = (unsigned short)(a2 >> 32);
    r.us[6] = (unsigned short)a3; r.us[7] = (unsigned short)(a3 >> 32);
    *(bf16x8*)dst = r.v;
}

// ---------------- persistent GRU kernel (barrier-free tagged dataflow) -----
// grid = 256 blocks, block = 512 threads (8 waves).
// g = bid>>5 (8 groups x 32 batch rows); l = bid&31 owns units [16l,16l+16).
// bid%8 == l%8 -> same-unit blocks share an XCD -> weight slices L2-local.
// Waves 0..5: gh (gate=w>>1, row-half=w&1); wave 6: x' tile; wave 7: staging.

__global__ __launch_bounds__(512, 2)
__attribute__((amdgpu_waves_per_eu(2, 2)))
void gru_persist(
    const __bf16* __restrict__ WhT_hi, const __bf16* __restrict__ WhT_lo,
    const __bf16* __restrict__ WxTP,
    const __bf16* __restrict__ Wih_hi, const __bf16* __restrict__ Wih_lo,
    const __bf16* __restrict__ Whh_hi, const __bf16* __restrict__ Whh_lo,
    const __bf16* __restrict__ XinP,
    const float* __restrict__ b_t, const float* __restrict__ b_ih,
    const float* __restrict__ b_hh,
    u32t* xpT, u32t* hbT,  // tagged (step<<16|bf16), 2-parity, MALL-coherent
    float* __restrict__ out)
{
    __shared__ __align__(16) char lds[57344];
    // [0,32768):      hT  32 rows x 1024B (bf16 k=512), XOR-swizzled
    // [32768,49152):  xT  32 rows x 512B  (bf16 k=256), XOR-swizzled
    // [49152,57344):  ex  [2 half][4 plane][16 row][16 unit] f32

    const int bid = blockIdx.x;
    const int g = bid >> 5, l = bid & 31;
    const int tid = threadIdx.x;
    const int w = tid >> 6, lane = tid & 63;
    const int lr = lane & 15, ko = (lane >> 4) << 3;

    char* hT = lds;
    char* xT = lds + 32768;
    float* ex = (float*)(lds + 49152);

    u32t* xpT_g = xpT + g * (32 * 256);
    u32t* hbT_g = hbT + g * (32 * 512);

    const int mw = (w == 6) ? (l & 1) : (w & 1);  // row-half for this wave
    const int gg = (w < 6) ? (w >> 1) : 0;        // gate (waves 0..5)

    // per-wave phase-A weight source (Whh slice / Wh slice)
    const __bf16 *srcH, *srcL;
    if (w < 6) {
        size_t j = (size_t)(gg * 512 + l * 16 + lr) * 512 + ko;
        srcH = Whh_hi + j; srcL = Whh_lo + j;
    } else {
        size_t j = (size_t)((l >> 1) * 16 + lr) * 512 + ko;
        srcH = WhT_hi + j; srcL = WhT_lo + j;
    }
    bf16x8 wxf = {};
    float bt_r = 0.f;
    if (w == 6) {
        int c = (l >> 1) * 16 + lr;
        wxf = *(const bf16x8*)(WxTP + (size_t)c * 32 + ko);
        bt_r = b_t[c];
    }

    // phase-B W_ih row pointers (waves 0..5), L2-resident streams
    const __bf16* pBh = Wih_hi + (size_t)(gg * 512 + l * 16 + lr) * 256 + ko;
    const __bf16* pBl = Wih_lo + (size_t)(gg * 512 + l * 16 + lr) * 256 + ko;

    // elementwise per-thread state: (row = tid>>4, unit = tid&15)
    const int erow = tid >> 4, eunit = tid & 15;
    float bi0, bi1, bi2, bh0, bh1, bh2;
    {
        int u = l * 16 + eunit;
        bi0 = b_ih[u]; bi1 = b_ih[512 + u]; bi2 = b_ih[1024 + u];
        bh0 = b_hh[u]; bh1 = b_hh[512 + u]; bh2 = b_hh[1024 + u];
    }
    float hreg = 0.f;  // fp32 h carried in-register across all steps
    const int exi = (erow >> 4) * 1024 + (erow & 15) * 16 + eunit;

    const int arow = mw * 16 + lr;
    const int swz = (arow & 7) << 4;
    const int abaseH = arow * 1024 + (lane >> 4) * 16;
    const int abaseX = arow * 512 + (lane >> 4) * 16;

    // opaque zero offset: defeats LICM so weight loads stay per-iteration,
    // issued at loop-top (overlap the h-poll), results held in VGPRs.
    u32t woff = 0;
    asm volatile("" : "+v"(woff));

    for (int t = 0; t < Tn; ++t) {
        const u32t xpar = (t & 1), hpar = (t & 1);
        const u32t tg = (u32t)(t + 1);

        // ---- issue phase-A weight loads (streamed from L2, used below) ----
        bf16x8 wHi[16], wLo[16];
        if (w < 7) {
            const char* pH = (const char*)srcH + woff;
            const char* pL = (const char*)srcL + woff;
#pragma unroll
            for (int k0 = 0; k0 < 16; ++k0) {
                wHi[k0] = *(const bf16x8*)(pH + k0 * 64);
                wLo[k0] = *(const bf16x8*)(pL + k0 * 64);
            }
        }

        // ---- stage h[t-1] -> hT (poll tags, strip, swizzle) ----
        {
            const u32t* hsrc = hbT_g + (hpar ^ 1) * PAR_H;
            const u32t want = (u32t)t;  // h[t-1] tag; t=0 -> 0 (memset)
#pragma unroll
            for (int e = 0; e < 4; ++e) {
                int idx = e * 512 + tid;        // 2048 chunks: 32 rows x 64 segs
                int row = idx >> 6, seg = idx & 63;
                poll_chunk(hsrc + row * 512 + seg * 8, want,
                           hT + ((row * 1024 + seg * 16) ^ ((row & 7) << 4)));
            }
        }
        __syncthreads();

        // ---- phase A: gh (waves 0-5) / x' (wave 6), K=512 hi/lo ----
        f32x4 accG = {};
        if (w < 7) {
#pragma unroll
            for (int k0 = 0; k0 < 16; ++k0) {
                bf16x8 a = *(const bf16x8*)(hT + ((abaseH + k0 * 64) ^ swz));
                accG = MFMA(a, wHi[k0], accG);
                accG = MFMA(a, wLo[k0], accG);
            }
        }
        if (w == 6) {
            bf16x8 ax = *(const bf16x8*)(XinP +
                ((size_t)t * 256 + g * 32 + mw * 16 + lr) * 32 + ko);
            accG = MFMA(ax, wxf, accG);
            int c = (l >> 1) * 16 + lr;
            u32t* xdst = xpT_g + xpar * PAR_X;
#pragma unroll
            for (int r = 0; r < 4; ++r) {
                int row = mw * 16 + (lane >> 4) * 4 + r;
                float v = accG[r] + bt_r;
                float e2 = __expf(2.f * v);
                ast32(xdst + row * 256 + c, tagval(tg, 1.f - 2.f / (e2 + 1.f)));
            }
        }

        // ---- waves 6,7: poll+stage x'[t] -> xT (overlaps waves 0-5 phA) ----
        if (w >= 6) {
            const u32t* xsrc = xpT_g + xpar * PAR_X;
            int local = tid - 384;  // 0..127
#pragma unroll
            for (int e = 0; e < 8; ++e) {
                int idx = e * 128 + local;      // 1024 chunks: 32 rows x 32 segs
                int row = idx >> 5, seg = idx & 31;
                poll_chunk(xsrc + row * 256 + seg * 8, tg,
                           xT + ((row * 512 + seg * 16) ^ ((row & 7) << 4)));
            }
        }
        __syncthreads();

        // ---- phase B: gx = x' @ W_ih.T (waves 0-5), K=256 hi/lo ----
        if (w < 6) {
            f32x4 accX = {};
#pragma unroll
            for (int k0 = 0; k0 < 8; ++k0) {
                bf16x8 a = *(const bf16x8*)(xT + ((abaseX + k0 * 64) ^ swz));
                bf16x8 bh = *(const bf16x8*)(pBh + k0 * 32);
                bf16x8 bl = *(const bf16x8*)(pBl + k0 * 32);
                accX = MFMA(a, bh, accX);
                accX = MFMA(a, bl, accX);
            }
            float* exm = ex + mw * 1024;
            if (gg < 2) {
#pragma unroll
                for (int r = 0; r < 4; ++r)
                    exm[gg * 256 + ((lane >> 4) * 4 + r) * 16 + lr] =
                        accG[r] + accX[r];
            } else {
#pragma unroll
                for (int r = 0; r < 4; ++r) {
                    exm[2 * 256 + ((lane >> 4) * 4 + r) * 16 + lr] = accX[r];
                    exm[3 * 256 + ((lane >> 4) * 4 + r) * 16 + lr] = accG[r];
                }
            }
        }
        __syncthreads();

        // ---- elementwise GRU update (all 512 threads, 1 elem each) ----
        {
            float pr = ex[exi]       + bi0 + bh0;
            float pz = ex[exi + 256] + bi1 + bh1;
            float xn = ex[exi + 512] + bi2;
            float hn = ex[exi + 768] + bh2;
            float rr = 1.f / (1.f + __expf(-pr));
            float zz = 1.f / (1.f + __expf(-pz));
            float e2 = __expf(2.f * (xn + rr * hn));
            float nn = 1.f - 2.f / (e2 + 1.f);
            hreg = (1.f - zz) * nn + zz * hreg;
            ast32(hbT_g + hpar * PAR_H + erow * 512 + l * 16 + eunit,
                  tagval(tg, hreg));
            if (t == Tn - 1)
                out[(size_t)(g * 32 + erow) * 512 + l * 16 + eunit] = hreg;
        }
        // no barrier: next iteration's h-poll self-synchronizes
    }
}

// ---------------- host launcher ----------------

extern "C" void kernel_launch(void* const* d_in, const int* in_sizes, int n_in,
                              void* d_out, int out_size, void* d_ws, size_t ws_size,
                              hipStream_t stream) {
    const float* x_l = (const float*)d_in[0];
    const float* x_e = (const float*)d_in[1];
    const float* Wh  = (const float*)d_in[2];
    const float* Wx  = (const float*)d_in[3];
    const float* bt  = (const float*)d_in[4];
    const float* Wih = (const float*)d_in[5];
    const float* Whh = (const float*)d_in[6];
    const float* bih = (const float*)d_in[7];
    const float* bhh = (const float*)d_in[8];

    char* ws = (char*)d_ws;
    __bf16* WhT_hi = (__bf16*)(ws + 0);          //  262144
    __bf16* WhT_lo = (__bf16*)(ws + 262144);     //  262144
    __bf16* WxTP   = (__bf16*)(ws + 524288);     //   16384
    __bf16* Wih_hi = (__bf16*)(ws + 540672);     //  786432
    __bf16* Wih_lo = (__bf16*)(ws + 1327104);    //  786432
    __bf16* Whh_hi = (__bf16*)(ws + 2113536);    // 1572864
    __bf16* Whh_lo = (__bf16*)(ws + 3686400);    // 1572864
    __bf16* XinP   = (__bf16*)(ws + 5259264);    // 5505024
    u32t*   xpT    = (u32t*)  (ws + 10764288);   // 2097152
    u32t*   hbT    = (u32t*)  (ws + 12861440);   // 4194304  -> total ~17.1 MB

    pack_wh<<<512, 256, 0, stream>>>(Wh, WhT_hi, WhT_lo);
    pack_wx<<<32, 256, 0, stream>>>(Wx, WxTP);
    pack_split<<<1536, 256, 0, stream>>>(Wih, Wih_hi, Wih_lo, 1536 * 256);
    pack_split<<<3072, 256, 0, stream>>>(Whh, Whh_hi, Whh_lo, 1536 * 512);
    pack_xin<<<10752, 256, 0, stream>>>(x_l, x_e, XinP);
    hipMemsetAsync(xpT, 0, 2097152, stream);   // clear tags (graph-replayed)
    hipMemsetAsync(hbT, 0, 4194304, stream);

    gru_persist<<<256, 512, 0, stream>>>(
        WhT_hi, WhT_lo, WxTP, Wih_hi, Wih_lo, Whh_hi, Whh_lo, XinP,
        bt, bih, bhh, xpT, hbT, (float*)d_out);
}

// Round 9
// 1952.932 us; speedup vs baseline: 2.9375x; 2.9375x over previous
//
#include <hip/hip_runtime.h>
#include <hip/hip_bf16.h>

// Problem constants
#define Bn 256
#define Tn 336
#define KE 16

typedef __attribute__((ext_vector_type(8))) __bf16 bf16x8;
typedef __attribute__((ext_vector_type(4))) float f32x4;
typedef unsigned long long u64t;
typedef unsigned int u32t;

#define MFMA(a, b, c) __builtin_amdgcn_mfma_f32_16x16x32_bf16((a), (b), (c), 0, 0, 0)

// ---------------- pack kernels (once per launch) ----------------

__global__ void pack_wh(const float* __restrict__ Wh, __bf16* __restrict__ hi,
                        __bf16* __restrict__ lo) {
    int i = blockIdx.x * 256 + threadIdx.x;  // 512*256
    int k = i >> 8, n = i & 255;
    float v = Wh[i];
    __bf16 h = (__bf16)v;
    hi[n * 512 + k] = h;
    lo[n * 512 + k] = (__bf16)(v - (float)h);
}

__global__ void pack_wx(const float* __restrict__ Wx, __bf16* __restrict__ out) {
    int i = blockIdx.x * 256 + threadIdx.x;  // 256*32
    int n = i >> 5, k = i & 31;
    out[i] = (__bf16)((k < 17) ? Wx[k * 256 + n] : 0.f);
}

__global__ void pack_split(const float* __restrict__ in, __bf16* __restrict__ hi,
                           __bf16* __restrict__ lo, int n) {
    int i = blockIdx.x * 256 + threadIdx.x;
    if (i >= n) return;
    float v = in[i];
    __bf16 h = (__bf16)v;
    hi[i] = h;
    lo[i] = (__bf16)(v - (float)h);
}

__global__ void pack_xin(const float* __restrict__ xl, const float* __restrict__ xe,
                         __bf16* __restrict__ out) {
    int i = blockIdx.x * 256 + threadIdx.x;  // 336*256*32
    int k = i & 31, b = (i >> 5) & 255, t = i >> 13;
    float v = 0.f;
    if (k == 0) v = xl[b * Tn + t];
    else if (k < 17) v = xe[(b * Tn + t) * KE + (k - 1)];
    out[i] = (__bf16)v;
}

// ---------------- MALL-coherent helpers (relaxed agent = sc1, no cache
// maintenance) — the HW-verified cross-CU exchange path (round 5) ----------

__device__ __forceinline__ bf16x8 ld16_mall(const __bf16* p) {
    union { u64t q[2]; bf16x8 v; } r;
    const u64t* q = (const u64t*)p;
    r.q[0] = __hip_atomic_load(q, __ATOMIC_RELAXED, __HIP_MEMORY_SCOPE_AGENT);
    r.q[1] = __hip_atomic_load(q + 1, __ATOMIC_RELAXED, __HIP_MEMORY_SCOPE_AGENT);
    return r.v;
}

__device__ __forceinline__ void st2_mall(__bf16* p, float f) {
    __bf16 h = (__bf16)f;
    union { __bf16 b; unsigned short u; } c; c.b = h;
    __hip_atomic_store((unsigned short*)p, c.u, __ATOMIC_RELAXED,
                       __HIP_MEMORY_SCOPE_AGENT);
}

// group barrier, RMW-free: each block stores VAL to its own flag dword
// (one 128B line per group); wave 0 polls the whole line, 1 load/lane.
// __syncthreads() drains vmcnt(0) before the flag store, so all prior sc1
// data stores are MALL-visible before the flag is (empirically verified:
// rounds 4-7 all numerically correct with this ordering).
#define GBAR(VAL)                                                              \
    do {                                                                       \
        __syncthreads();                                                       \
        if (tid == 0)                                                          \
            __hip_atomic_store(fl + l, (u32t)(VAL), __ATOMIC_RELAXED,          \
                               __HIP_MEMORY_SCOPE_AGENT);                      \
        if (w == 0) {                                                          \
            const u32t* fp = fl + (lane & 31);                                 \
            for (;;) {                                                         \
                u32t v = __hip_atomic_load(fp, __ATOMIC_RELAXED,               \
                                           __HIP_MEMORY_SCOPE_AGENT);          \
                if (__all(v >= (u32t)(VAL))) break;                            \
                __builtin_amdgcn_s_sleep(1);                                   \
            }                                                                  \
        }                                                                      \
        __syncthreads();                                                       \
    } while (0)

// ---------------- persistent GRU kernel ----------------
// grid = 256 blocks (1/CU), block = 512 threads (8 waves). group g = bid&7
// (32 blocks, batch rows [g*32, g*32+32)); block l = bid>>3 owns hidden
// units [16l,16l+16). Waves 0..5: gh (gate=w>>1, row-half=w&1) with W_hh
// hi/lo PINNED in registers via in-loop opaque asm (loop-carried values,
// un-rematerializable). Wave 6: x' tile, Wh pinned. Wave 7: staging only.
// W_ih slice lives in LDS (staged once); phase B is LDS+regs only.

__global__ __launch_bounds__(512, 2)
__attribute__((amdgpu_waves_per_eu(2, 2)))
void gru_persist(
    const __bf16* __restrict__ WhT_hi, const __bf16* __restrict__ WhT_lo,
    const __bf16* __restrict__ WxTP,
    const __bf16* __restrict__ Wih_hi, const __bf16* __restrict__ Wih_lo,
    const __bf16* __restrict__ Whh_hi, const __bf16* __restrict__ Whh_lo,
    const __bf16* __restrict__ XinP,
    const float* __restrict__ b_t, const float* __restrict__ b_ih,
    const float* __restrict__ b_hh,
    __bf16* xp, __bf16* hbf,  // shared via MALL-coherent sc1 ops
    u32t* cnt, float* __restrict__ out)
{
    __shared__ __align__(16) char lds[106496];
    // [0,32768):        hT  32 rows x 1024B (bf16 k=512), XOR-swizzled
    // [32768,49152):    xT  32 rows x 512B  (bf16 k=256), XOR-swizzled
    // [49152,57344):    ex  [2 half][4 plane][16 row][16 unit] f32
    // [57344,106496):   wB  W_ih slice: hi 48x512B | lo 48x512B, swizzled

    const int bid = blockIdx.x;
    const int g = bid & 7, l = bid >> 3;
    const int tid = threadIdx.x;
    const int w = tid >> 6, lane = tid & 63;
    const int lr = lane & 15, ko = (lane >> 4) << 3;

    char* hT = lds;
    char* xT = lds + 32768;
    float* ex = (float*)(lds + 49152);
    char* wB = lds + 57344;

    __bf16* hbf_g = hbf + g * (32 * 512);
    __bf16* xp_g  = xp  + g * (32 * 256);
    u32t* fl = cnt + g * 32;  // one 128B flag line per group

    const int mw = (w == 6) ? (l & 1) : (w & 1);  // row-half for this wave
    const int gg = (w < 6) ? (w >> 1) : 0;        // gate (waves 0..5)

    // ---- stage W_ih slice -> wB LDS (once; reused 336 steps) ----
#pragma unroll
    for (int e = 0; e < 3; ++e) {
        int idx = e * 512 + tid;            // 1536 chunks: 48 rows x 32 segs
        int row = idx >> 5, seg = idx & 31; // row: gate*16 + unit
        int gate = row >> 4, r = row & 15;
        size_t src = (size_t)(gate * 512 + l * 16 + r) * 256 + seg * 8;
        int dst = (row * 512 + seg * 16) ^ ((row & 7) << 4);
        *(bf16x8*)(wB + dst)         = *(const bf16x8*)(Wih_hi + src);
        *(bf16x8*)(wB + 24576 + dst) = *(const bf16x8*)(Wih_lo + src);
    }

    // ---- load phase-A weights once; pinned in-loop below ----
    const __bf16 *srcH, *srcL;
    if (w < 6) {
        size_t j = (size_t)(gg * 512 + l * 16 + lr) * 512 + ko;
        srcH = Whh_hi + j; srcL = Whh_lo + j;
    } else if (w == 6) {
        size_t j = (size_t)((l >> 1) * 16 + lr) * 512 + ko;
        srcH = WhT_hi + j; srcL = WhT_lo + j;
    } else {
        srcH = Whh_hi + ko; srcL = Whh_lo + ko;  // dummy (valid) for wave 7
    }
    f32x4 wHi[16], wLo[16];
#pragma unroll
    for (int k0 = 0; k0 < 16; ++k0) {
        wHi[k0] = *(const f32x4*)(srcH + k0 * 32);
        wLo[k0] = *(const f32x4*)(srcL + k0 * 32);
    }
    bf16x8 wxf = {};
    float bt_r = 0.f;
    if (w == 6) {
        int c = (l >> 1) * 16 + lr;
        wxf = *(const bf16x8*)(WxTP + (size_t)c * 32 + ko);
        bt_r = b_t[c];
    }

    // elementwise per-thread state: (row = tid>>4, unit = tid&15)
    const int erow = tid >> 4, eunit = tid & 15;
    float bi0, bi1, bi2, bh0, bh1, bh2;
    {
        int u = l * 16 + eunit;
        bi0 = b_ih[u]; bi1 = b_ih[512 + u]; bi2 = b_ih[1024 + u];
        bh0 = b_hh[u]; bh1 = b_hh[512 + u]; bh2 = b_hh[1024 + u];
    }
    float hreg = 0.f;  // fp32 h carried in-register across all steps
    const int exi = (erow >> 4) * 1024 + (erow & 15) * 16 + eunit;

    // MFMA fragment LDS addressing
    const int arow = mw * 16 + lr;
    const int swz = (arow & 7) << 4;
    const int abaseH = arow * 1024 + (lane >> 4) * 16;
    const int abaseX = arow * 512 + (lane >> 4) * 16;
    const int brow = gg * 16 + lr;                 // wB B-fragment row
    const int bswz = (brow & 7) << 4;
    const int bbase = brow * 512 + (lane >> 4) * 16;

    for (int t = 0; t < Tn; ++t) {
        // ---- pin phase-A weights: opaque in-loop touch makes them
        //      loop-carried register values (cannot be rematerialized) ----
#pragma unroll
        for (int k0 = 0; k0 < 16; ++k0)
            asm volatile("" : "+v"(wHi[k0]), "+v"(wLo[k0]));

        // ---- stage h[t-1] -> hT (sc1 loads, swizzle into LDS) ----
#pragma unroll
        for (int e = 0; e < 4; ++e) {
            int r = e * 8 + w;
            bf16x8 v = ld16_mall(hbf_g + r * 512 + lane * 8);
            *(bf16x8*)(hT + ((r * 1024 + lane * 16) ^ ((r & 7) << 4))) = v;
        }
        __syncthreads();

        // ---- phase A: gh (waves 0-5) / x' (wave 6), K=512 hi/lo ----
        f32x4 accG = {};
        if (w < 7) {
            f32x4 aH = {}, aL = {};
#pragma unroll
            for (int k0 = 0; k0 < 16; ++k0) {
                bf16x8 a = *(const bf16x8*)(hT + ((abaseH + k0 * 64) ^ swz));
                aH = MFMA(a, __builtin_bit_cast(bf16x8, wHi[k0]), aH);
                aL = MFMA(a, __builtin_bit_cast(bf16x8, wLo[k0]), aL);
            }
            if (w == 6) {
                bf16x8 ax = *(const bf16x8*)(XinP +
                    ((size_t)t * 256 + g * 32 + mw * 16 + lr) * 32 + ko);
                aH = MFMA(ax, wxf, aH);
            }
            accG = aH + aL;
        }
        if (w == 6) {
            int c = (l >> 1) * 16 + lr;
#pragma unroll
            for (int r = 0; r < 4; ++r) {
                int row = mw * 16 + (lane >> 4) * 4 + r;
                float v = accG[r] + bt_r;
                float e2 = __expf(2.f * v);
                st2_mall(xp_g + row * 256 + c, 1.f - 2.f / (e2 + 1.f));
            }
        }

        GBAR(2 * t + 1);  // x' MALL-visible group-wide

        // ---- stage x'[t] -> xT (sc1 loads, swizzle into LDS) ----
#pragma unroll
        for (int e = 0; e < 2; ++e) {
            int r = e * 16 + (tid >> 5);
            int kc = tid & 31;
            bf16x8 v = ld16_mall(xp_g + r * 256 + kc * 8);
            *(bf16x8*)(xT + ((r * 512 + kc * 16) ^ ((r & 7) << 4))) = v;
        }
        __syncthreads();

        // ---- phase B: gx = x' @ W_ih.T (waves 0-5), K=256 hi/lo,
        //      B-fragments from LDS (wB), A-fragments from LDS (xT) ----
        if (w < 6) {
            f32x4 xH = {}, xL = {};
#pragma unroll
            for (int k0 = 0; k0 < 8; ++k0) {
                bf16x8 a  = *(const bf16x8*)(xT + ((abaseX + k0 * 64) ^ swz));
                bf16x8 bh = *(const bf16x8*)(wB + ((bbase + k0 * 64) ^ bswz));
                bf16x8 bl = *(const bf16x8*)(wB + 24576 +
                                             ((bbase + k0 * 64) ^ bswz));
                xH = MFMA(a, bh, xH);
                xL = MFMA(a, bl, xL);
            }
            f32x4 accX = xH + xL;
            float* exm = ex + mw * 1024;
            if (gg < 2) {
#pragma unroll
                for (int r = 0; r < 4; ++r)
                    exm[gg * 256 + ((lane >> 4) * 4 + r) * 16 + lr] =
                        accG[r] + accX[r];
            } else {
#pragma unroll
                for (int r = 0; r < 4; ++r) {
                    exm[2 * 256 + ((lane >> 4) * 4 + r) * 16 + lr] = accX[r];
                    exm[3 * 256 + ((lane >> 4) * 4 + r) * 16 + lr] = accG[r];
                }
            }
        }
        __syncthreads();

        // ---- elementwise GRU update (all 512 threads, 1 elem each) ----
        {
            float pr = ex[exi]       + bi0 + bh0;
            float pz = ex[exi + 256] + bi1 + bh1;
            float xn = ex[exi + 512] + bi2;
            float hn = ex[exi + 768] + bh2;
            float rr = 1.f / (1.f + __expf(-pr));
            float zz = 1.f / (1.f + __expf(-pz));
            float e2 = __expf(2.f * (xn + rr * hn));
            float nn = 1.f - 2.f / (e2 + 1.f);
            hreg = (1.f - zz) * nn + zz * hreg;
            st2_mall(hbf_g + erow * 512 + l * 16 + eunit, hreg);
            if (t == Tn - 1)
                out[(size_t)(g * 32 + erow) * 512 + l * 16 + eunit] = hreg;
        }

        if (t != Tn - 1) GBAR(2 * t + 2);  // h MALL-visible group-wide
    }
}

// ---------------- host launcher ----------------

extern "C" void kernel_launch(void* const* d_in, const int* in_sizes, int n_in,
                              void* d_out, int out_size, void* d_ws, size_t ws_size,
                              hipStream_t stream) {
    const float* x_l = (const float*)d_in[0];
    const float* x_e = (const float*)d_in[1];
    const float* Wh  = (const float*)d_in[2];
    const float* Wx  = (const float*)d_in[3];
    const float* bt  = (const float*)d_in[4];
    const float* Wih = (const float*)d_in[5];
    const float* Whh = (const float*)d_in[6];
    const float* bih = (const float*)d_in[7];
    const float* bhh = (const float*)d_in[8];

    char* ws = (char*)d_ws;
    __bf16* WhT_hi = (__bf16*)(ws + 0);          //  262144
    __bf16* WhT_lo = (__bf16*)(ws + 262144);     //  262144
    __bf16* WxTP   = (__bf16*)(ws + 524288);     //   16384
    __bf16* Wih_hi = (__bf16*)(ws + 540672);     //  786432
    __bf16* Wih_lo = (__bf16*)(ws + 1327104);    //  786432
    __bf16* Whh_hi = (__bf16*)(ws + 2113536);    // 1572864
    __bf16* Whh_lo = (__bf16*)(ws + 3686400);    // 1572864
    __bf16* XinP   = (__bf16*)(ws + 5259264);    // 5505024
    __bf16* xp     = (__bf16*)(ws + 10764288);   //  131072
    __bf16* hbf    = (__bf16*)(ws + 10895360);   //  262144
    u32t*   cnt    = (u32t*)  (ws + 11157504);   //    1024  -> total ~11.2 MB

    pack_wh<<<512, 256, 0, stream>>>(Wh, WhT_hi, WhT_lo);
    pack_wx<<<32, 256, 0, stream>>>(Wx, WxTP);
    pack_split<<<1536, 256, 0, stream>>>(Wih, Wih_hi, Wih_lo, 1536 * 256);
    pack_split<<<3072, 256, 0, stream>>>(Whh, Whh_hi, Whh_lo, 1536 * 512);
    pack_xin<<<10752, 256, 0, stream>>>(x_l, x_e, XinP);
    hipMemsetAsync(hbf, 0, 262144, stream);
    hipMemsetAsync(cnt, 0, 1024, stream);

    gru_persist<<<256, 512, 0, stream>>>(
        WhT_hi, WhT_lo, WxTP, Wih_hi, Wih_lo, Whh_hi, Whh_lo, XinP,
        bt, bih, bhh, xp, hbf, cnt, (float*)d_out);
}